// Round 12
// baseline (14182.884 us; speedup 1.0000x reference)
//
#include <hip/hip_runtime.h>
#include <hip/hip_bf16.h>
#include <math.h>

typedef short bf16x8 __attribute__((ext_vector_type(8)));
typedef float f32x4 __attribute__((ext_vector_type(4)));
typedef unsigned short u16;

#define NT 64
#define NB 512
#define NS 256
#define NA 64
#define NBEL 1024

// d_out element offsets (f32 elements)
#define OUT_B      0
#define OUT_SPRI   33554432
#define OUT_MUPRI  41943040
#define OUT_STDPRI 50331648
#define OUT_SPOS   58720256
#define OUT_MUPOS  67108864
#define OUT_STDPOS 75497472

__device__ __forceinline__ f32x4 mfma16(bf16x8 a, bf16x8 b, f32x4 c) {
  return __builtin_amdgcn_mfma_f32_16x16x32_bf16(a, b, c, 0, 0, 0);
}

__device__ __forceinline__ u16 f2bf(float f) {
  union { float f; unsigned u; } v; v.f = f;
  return (u16)((v.u + 0x7FFFu + ((v.u >> 16) & 1u)) >> 16);
}
__device__ __forceinline__ float bf2f(u16 h) {
  union { unsigned u; float f; } v; v.u = ((unsigned)h) << 16; return v.f;
}

__device__ __forceinline__ bf16x8 ld8bf(const u16* p) { return *(const bf16x8*)p; }

__device__ __forceinline__ bf16x8 cvt8(const float* p) {
  const float4 lo = *(const float4*)p;
  const float4 hi = *(const float4*)(p + 4);
  bf16x8 v;
  v[0] = (short)f2bf(lo.x); v[1] = (short)f2bf(lo.y);
  v[2] = (short)f2bf(lo.z); v[3] = (short)f2bf(lo.w);
  v[4] = (short)f2bf(hi.x); v[5] = (short)f2bf(hi.y);
  v[6] = (short)f2bf(hi.z); v[7] = (short)f2bf(hi.w);
  return v;
}

__device__ __forceinline__ float sigm(float x) { return 1.f / (1.f + __expf(-x)); }
__device__ __forceinline__ float softplus_(float x) {
  if (x > 20.f) return x;
  return log1pf(__expf(x));
}

#define ZACC(acc) { acc[0][0] = (f32x4){0.f,0.f,0.f,0.f}; acc[0][1] = (f32x4){0.f,0.f,0.f,0.f}; \
                    acc[1][0] = (f32x4){0.f,0.f,0.f,0.f}; acc[1][1] = (f32x4){0.f,0.f,0.f,0.f}; }

#define Q4(acc, a0v, a1v, b0v, b1v) \
  acc[0][0] = mfma16(a0v, b0v, acc[0][0]); \
  acc[0][1] = mfma16(a0v, b1v, acc[0][1]); \
  acc[1][0] = mfma16(a1v, b0v, acc[1][0]); \
  acc[1][1] = mfma16(a1v, b1v, acc[1][1]);

__device__ __forceinline__ void gtile(f32x4 (&acc)[2][2],
    const u16* __restrict__ A, int lda, const u16* __restrict__ B, int ldb,
    int K, int r16, int kq) {
  const u16* A0 = A + r16 * lda + kq * 8;
  const u16* A1 = A0 + 16 * lda;
  const u16* B0 = B + (size_t)r16 * ldb + kq * 8;
  const u16* B1 = B0 + 16 * ldb;
#pragma unroll 4
  for (int k = 0; k < K; k += 32) {
    bf16x8 a0 = ld8bf(A0 + k), a1 = ld8bf(A1 + k);
    bf16x8 b0 = ld8bf(B0 + k), b1 = ld8bf(B1 + k);
    Q4(acc, a0, a1, b0, b1);
  }
}
__device__ __forceinline__ void gtileF(f32x4 (&acc)[2][2],
    const float* __restrict__ A, int lda, const u16* __restrict__ B, int ldb,
    int K, int r16, int kq) {
  const float* A0 = A + r16 * lda + kq * 8;
  const float* A1 = A0 + 16 * lda;
  const u16* B0 = B + (size_t)r16 * ldb + kq * 8;
  const u16* B1 = B0 + 16 * ldb;
#pragma unroll 2
  for (int k = 0; k < K; k += 32) {
    bf16x8 a0 = cvt8(A0 + k), a1 = cvt8(A1 + k);
    bf16x8 b0 = ld8bf(B0 + k), b1 = ld8bf(B1 + k);
    Q4(acc, a0, a1, b0, b1);
  }
}

__device__ __forceinline__ void red_write(float* L, f32x4 (&acc)[2][2], int l) {
  const int base = l * 16;
#pragma unroll
  for (int i = 0; i < 2; ++i)
#pragma unroll
    for (int j = 0; j < 2; ++j)
#pragma unroll
      for (int q = 0; q < 4; ++q)
        L[base + (i * 2 + j) * 4 + q] = acc[i][j][q];
}
__device__ __forceinline__ void red_add(const float* L, f32x4 (&acc)[2][2], int l) {
  const int base = l * 16;
#pragma unroll
  for (int i = 0; i < 2; ++i)
#pragma unroll
    for (int j = 0; j < 2; ++j)
#pragma unroll
      for (int q = 0; q < 4; ++q)
        acc[i][j][q] += L[base + (i * 2 + j) * 4 + q];
}

// -------- device-scope flag sync (proven R7-R11) --------
__device__ __forceinline__ void setflag_blk(unsigned* f) {
  __syncthreads();
  if (threadIdx.x == 0)
    __hip_atomic_fetch_add(f, 1u, __ATOMIC_RELEASE, __HIP_MEMORY_SCOPE_AGENT);
}
__device__ __forceinline__ void waitflag_blk(unsigned* f, unsigned target) {
  if (threadIdx.x == 0) {
    while (__hip_atomic_load(f, __ATOMIC_RELAXED, __HIP_MEMORY_SCOPE_AGENT) < target)
      __builtin_amdgcn_s_sleep(2);
    (void)__hip_atomic_load(f, __ATOMIC_ACQUIRE, __HIP_MEMORY_SCOPE_AGENT);
  }
  __syncthreads();
}

// -------- P0: weights f32 -> bf16 --------
__global__ __launch_bounds__(256) void cvt_weights_k(
    const float* __restrict__ wsa, const float* __restrict__ wih,
    const float* __restrict__ whh, const float* __restrict__ wbpri,
    const float* __restrict__ wspri, const float* __restrict__ wbpos,
    const float* __restrict__ wspos, u16* __restrict__ dst) {
  const int S0 = 327680;
  const int S1 = S0 + 3145728;
  const int S2 = S1 + 3145728;
  const int S3 = S2 + 1048576;
  const int S4 = S3 + 524288;
  const int S5 = S4 + 2097152;
  const int S6 = S5 + 524288;
  for (int i = blockIdx.x * blockDim.x + threadIdx.x; i < S6;
       i += gridDim.x * blockDim.x) {
    float v;
    if (i < S0) v = wsa[i];
    else if (i < S1) v = wih[i - S0];
    else if (i < S2) v = whh[i - S1];
    else if (i < S3) v = wbpri[i - S2];
    else if (i < S4) v = wspri[i - S3];
    else if (i < S5) v = wbpos[i - S4];
    else v = wspos[i - S5];
    dst[i] = f2bf(v);
  }
}

// -------- P1: init carries + zero flags --------
__global__ __launch_bounds__(256) void init_carry_k(
    const float* __restrict__ s0, const float* __restrict__ b0,
    const float* __restrict__ Mptr, u16* __restrict__ smask,
    u16* __restrict__ bbf, float* __restrict__ hf,
    unsigned* __restrict__ flags) {
  for (int i = blockIdx.x * blockDim.x + threadIdx.x; i < NB * NBEL;
       i += gridDim.x * blockDim.x) {
    float b = b0[i];
    bbf[i] = f2bf(b);
    hf[i] = b;
    if (i < NB * NS) {
      int row = i >> 8;
      smask[i] = f2bf(s0[i] * Mptr[row]);
    }
    if (i < 4 * NT) flags[i] = 0;
  }
}

// -------- device pieces --------

// spri: 32 blocks (8 x 4), K-split 8-wave
__device__ __forceinline__ void dev_spri(
    int g, int wid, int kh, int r16, int kq, int l, int tt,
    const u16* __restrict__ hpri, const u16* __restrict__ wspri,
    const float* __restrict__ bspri, const float* __restrict__ npri,
    float* __restrict__ out, float* lred0, float* lred1) {
  const int bm = g >> 2, bn = g & 3;
  const int row0 = bm * 64 + (wid >> 1) * 32;
  const int c0 = bn * 64 + (wid & 1) * 32;
  f32x4 am[2][2], ah[2][2];
  ZACC(am); ZACC(ah);
  const u16* A0 = hpri + (row0 + r16) * NBEL + kh * 512 + kq * 8;
  const u16* A1 = A0 + 16 * NBEL;
  const u16* Bm0 = wspri + (size_t)(c0 + r16) * NBEL + kh * 512 + kq * 8;
  const u16* Bm1 = Bm0 + 16 * NBEL;
  const u16* Bh0 = wspri + (size_t)(c0 + 256 + r16) * NBEL + kh * 512 + kq * 8;
  const u16* Bh1 = Bh0 + 16 * NBEL;
#pragma unroll 4
  for (int k = 0; k < 512; k += 32) {
    bf16x8 a0 = ld8bf(A0 + k), a1 = ld8bf(A1 + k);
    bf16x8 m0 = ld8bf(Bm0 + k), m1 = ld8bf(Bm1 + k);
    Q4(am, a0, a1, m0, m1);
    bf16x8 h0 = ld8bf(Bh0 + k), h1 = ld8bf(Bh1 + k);
    Q4(ah, a0, a1, h0, h1);
  }
  if (kh == 1) {
    red_write(lred0, am, l);
    red_write(lred1, ah, l);
  }
  __syncthreads();
  if (kh == 0) {
    red_add(lred0, am, l);
    red_add(lred1, ah, l);
#pragma unroll
    for (int i = 0; i < 2; ++i)
#pragma unroll
      for (int j = 0; j < 2; ++j)
#pragma unroll
        for (int q = 0; q < 4; ++q) {
          const int row = row0 + i * 16 + kq * 4 + q;
          const int c = c0 + j * 16 + r16;
          const size_t idx = (size_t)tt * (NB * NS) + (size_t)row * NS + c;
          const float mu = am[i][j][q] + bspri[c];
          const float hp = ah[i][j][q] + bspri[c + 256];
          const float sd = softplus_(hp) + 0.1f;
          out[OUT_SPRI + idx] = mu + sd * npri[idx];
          out[OUT_MUPRI + idx] = mu;
          out[OUT_STDPRI + idx] = sd;
        }
  }
}

// x: 64 blocks (8 x 8), 8-wave full-K 64x128 tiles
__device__ __forceinline__ void dev_x64(
    int g, int wid8, int r16, int kq, int t,
    const u16* __restrict__ smask, const float* __restrict__ Af,
    const u16* __restrict__ wsa, const float* __restrict__ bsa,
    u16* __restrict__ xg) {
  const int row0 = (g >> 3) * 64 + (wid8 >> 2) * 32;
  const int col0 = (g & 7) * 128 + (wid8 & 3) * 32;
  f32x4 acc[2][2]; ZACC(acc);
  gtile(acc, smask + row0 * NS, NS, wsa + (size_t)col0 * 320, 320, 256, r16, kq);
  gtileF(acc, Af + (size_t)t * (NB * NA) + (size_t)row0 * NA, NA,
         wsa + (size_t)col0 * 320 + 256, 320, 64, r16, kq);
#pragma unroll
  for (int i = 0; i < 2; ++i)
#pragma unroll
    for (int j = 0; j < 2; ++j)
#pragma unroll
      for (int q = 0; q < 4; ++q) {
        const int row = row0 + i * 16 + kq * 4 + q;
        const int col = col0 + j * 16 + r16;
        xg[row * NBEL + col] = f2bf(fmaxf(acc[i][j][q] + bsa[col], 0.f));
      }
}

// hbO (prologue): 64 blocks (8 x 8)
__device__ __forceinline__ void dev_hbO64(
    int g, int wid8, int r16, int kq,
    const float* __restrict__ OfT, const u16* __restrict__ wbpos,
    float* __restrict__ hbOn) {
  const int row0 = (g >> 3) * 64 + (wid8 >> 2) * 32;
  const int col0 = (g & 7) * 128 + (wid8 & 3) * 32;
  f32x4 acc[2][2]; ZACC(acc);
  gtileF(acc, OfT + (size_t)row0 * NBEL, NBEL,
         wbpos + (size_t)col0 * 2048 + 1024, 2048, 1024, r16, kq);
#pragma unroll
  for (int i = 0; i < 2; ++i)
#pragma unroll
    for (int j = 0; j < 2; ++j)
#pragma unroll
      for (int q = 0; q < 4; ++q) {
        const int row = row0 + i * 16 + kq * 4 + q;
        const int col = col0 + j * 16 + r16;
        hbOn[row * NBEL + col] = acc[i][j][q];
      }
}

// hbO (in-step): 32 blocks (8 x 4), 2 passes of 64x128
__device__ __forceinline__ void dev_hbO32(
    int g, int wid8, int r16, int kq,
    const float* __restrict__ OfT, const u16* __restrict__ wbpos,
    float* __restrict__ hbOn) {
  const int row0 = (g >> 2) * 64 + (wid8 >> 2) * 32;
#pragma unroll
  for (int jt = 0; jt < 2; ++jt) {
    const int col0 = (g & 3) * 256 + jt * 128 + (wid8 & 3) * 32;
    f32x4 acc[2][2]; ZACC(acc);
    gtileF(acc, OfT + (size_t)row0 * NBEL, NBEL,
           wbpos + (size_t)col0 * 2048 + 1024, 2048, 1024, r16, kq);
#pragma unroll
    for (int i = 0; i < 2; ++i)
#pragma unroll
      for (int j = 0; j < 2; ++j)
#pragma unroll
        for (int q = 0; q < 4; ++q) {
          const int row = row0 + i * 16 + kq * 4 + q;
          const int col = col0 + j * 16 + r16;
          hbOn[row * NBEL + col] = acc[i][j][q];
        }
  }
}

// gh (prologue): 96 blocks (8 x 12)
__device__ __forceinline__ void dev_gh96(
    int g, int wid8, int r16, int kq,
    const u16* __restrict__ bsrc, const u16* __restrict__ whh,
    const float* __restrict__ bhh, u16* __restrict__ ghn) {
  const int bm = g / 12, bc = g % 12;
  const int row0 = bm * 64 + (wid8 >> 2) * 32;
#pragma unroll
  for (int jt = 0; jt < 2; ++jt) {
    const int col0 = bc * 256 + (wid8 & 3) * 32 + jt * 128;
    f32x4 acc[2][2]; ZACC(acc);
    gtile(acc, bsrc + row0 * NBEL, NBEL, whh + (size_t)col0 * NBEL, NBEL,
          1024, r16, kq);
#pragma unroll
    for (int i = 0; i < 2; ++i)
#pragma unroll
      for (int j = 0; j < 2; ++j)
#pragma unroll
        for (int q = 0; q < 4; ++q) {
          const int row = row0 + i * 16 + kq * 4 + q;
          const int col = col0 + j * 16 + r16;
          ghn[row * 3072 + col] = f2bf(acc[i][j][q] + bhh[col]);
        }
  }
}

// gh (in-step): 48 blocks (8 x 6), 4 passes of 64x128
__device__ __forceinline__ void dev_gh48(
    int g, int wid8, int r16, int kq,
    const u16* __restrict__ bsrc, const u16* __restrict__ whh,
    const float* __restrict__ bhh, u16* __restrict__ ghn) {
  const int bm = g / 6, bc = g % 6;
  const int row0 = bm * 64 + (wid8 >> 2) * 32;
#pragma unroll
  for (int jt = 0; jt < 4; ++jt) {
    const int col0 = bc * 512 + jt * 128 + (wid8 & 3) * 32;
    f32x4 acc[2][2]; ZACC(acc);
    gtile(acc, bsrc + row0 * NBEL, NBEL, whh + (size_t)col0 * NBEL, NBEL,
          1024, r16, kq);
#pragma unroll
    for (int i = 0; i < 2; ++i)
#pragma unroll
      for (int j = 0; j < 2; ++j)
#pragma unroll
        for (int q = 0; q < 4; ++q) {
          const int row = row0 + i * 16 + kq * 4 + q;
          const int col = col0 + j * 16 + r16;
          ghn[row * 3072 + col] = f2bf(acc[i][j][q] + bhh[col]);
        }
  }
}

// bpri (in-step): 32 blocks (8 x 4), 2 passes
__device__ __forceinline__ void dev_bpri32(
    int g, int wid8, int r16, int kq,
    const u16* __restrict__ bcur, const u16* __restrict__ wbpri,
    const float* __restrict__ bbpri, u16* __restrict__ hpri) {
  const int row0 = (g >> 2) * 64 + (wid8 >> 2) * 32;
#pragma unroll
  for (int jt = 0; jt < 2; ++jt) {
    const int col0 = (g & 3) * 256 + jt * 128 + (wid8 & 3) * 32;
    f32x4 acc[2][2]; ZACC(acc);
    gtile(acc, bcur + row0 * NBEL, NBEL, wbpri + (size_t)col0 * NBEL, NBEL,
          1024, r16, kq);
#pragma unroll
    for (int i = 0; i < 2; ++i)
#pragma unroll
      for (int j = 0; j < 2; ++j)
#pragma unroll
        for (int q = 0; q < 4; ++q) {
          const int row = row0 + i * 16 + kq * 4 + q;
          const int col = col0 + j * 16 + r16;
          hpri[row * NBEL + col] = f2bf(fmaxf(acc[i][j][q] + bbpri[col], 0.f));
        }
  }
}

// ======================= kX0: x(0) [0..63] | hbO(0) [64..127] | gh(0) [128..223] =======================
__global__ __launch_bounds__(512, 2) void kX0(
    const u16* __restrict__ smask, const float* __restrict__ Af,
    const u16* __restrict__ wsa, const float* __restrict__ bsa,
    u16* __restrict__ xg, const float* __restrict__ Of,
    const u16* __restrict__ wbpos, float* __restrict__ hbO0,
    const u16* __restrict__ bbf, const u16* __restrict__ whh,
    const float* __restrict__ bhh, u16* __restrict__ ghA) {
  const int l = threadIdx.x & 63, r16 = l & 15, kq = l >> 4;
  const int wid8 = threadIdx.x >> 6;
  if (blockIdx.x < 64) {
    dev_x64(blockIdx.x, wid8, r16, kq, 0, smask, Af, wsa, bsa, xg);
  } else if (blockIdx.x < 128) {
    dev_hbO64(blockIdx.x - 64, wid8, r16, kq, Of, wbpos, hbO0);
  } else {
    dev_gh96(blockIdx.x - 128, wid8, r16, kq, bbf, whh, bhh, ghA);
  }
}

// ======================= kS: one kernel per step (496 blocks) =======================
// [0..127]   GRU (gi K-split + epilogue)            -> fG
// [128..159] spri(t-1) (reads hpriPrev)             (no wait)
// [160..287] hbB   (wait fG=128)                    -> fH
// [288..319] bpri  (wait fG=128, writes hpriCur)    -> fB
// [320..367] gh48(t+1)  (wait fG=128)
// [368..399] hbO32(t+1) (no wait)
// [400..431] spos  (wait fH=128)                    -> fS
// [432..495] x64(t+1) (wait fS=32) | spri(63) tail (wait fB=32)
__global__ __launch_bounds__(512, 2) void kS(
    const u16* __restrict__ xg, const u16* __restrict__ wih,
    const float* __restrict__ bih, const u16* __restrict__ ghc,
    float* __restrict__ hf, u16* __restrict__ bbf, float* __restrict__ out,
    const u16* __restrict__ hpriPrev, u16* __restrict__ hpriCur,
    const u16* __restrict__ wspri, const float* __restrict__ bspri,
    const float* __restrict__ npri,
    const u16* __restrict__ wbpos, const float* __restrict__ bbpos,
    const float* __restrict__ hbOc, u16* __restrict__ hbbf,
    const u16* __restrict__ wbpri, const float* __restrict__ bbpri,
    const u16* __restrict__ whh, const float* __restrict__ bhh,
    u16* __restrict__ ghn,
    const float* __restrict__ Of, float* __restrict__ hbOn,
    const u16* __restrict__ wspos, const float* __restrict__ bspos,
    const float* __restrict__ npos, const float* __restrict__ Mptr,
    u16* __restrict__ smask,
    const float* __restrict__ Af, const u16* __restrict__ wsa,
    const float* __restrict__ bsa,
    unsigned* __restrict__ fG, unsigned* __restrict__ fH,
    unsigned* __restrict__ fS, unsigned* __restrict__ fB, int t) {
  __shared__ float lred[4][3][1024];  // 48KB
  const int l = threadIdx.x & 63, r16 = l & 15, kq = l >> 4;
  const int wid8 = threadIdx.x >> 6;
  const int wid = wid8 & 3, kh = wid8 >> 2;
  if (blockIdx.x < 128) {
    // ---- GRU: gi K-split + epilogue with precomputed gh ----
    const int g = blockIdx.x, bm = g >> 4, bn = g & 15;
    const int row0 = bm * 64 + (wid >> 1) * 32;
    const int col0 = bn * 64 + (wid & 1) * 32;
    f32x4 ar[2][2], az[2][2], an[2][2];
    ZACC(ar); ZACC(az); ZACC(an);
    const u16* A0 = xg + (row0 + r16) * NBEL + kh * 512 + kq * 8;
    const u16* A1 = A0 + 16 * NBEL;
    const u16* Br0 = wih + (size_t)(col0 + r16) * NBEL + kh * 512 + kq * 8;
    const u16* Br1 = Br0 + 16 * NBEL;
    const u16* Bz0 = wih + (size_t)(col0 + 1024 + r16) * NBEL + kh * 512 + kq * 8;
    const u16* Bz1 = Bz0 + 16 * NBEL;
    const u16* Bn0 = wih + (size_t)(col0 + 2048 + r16) * NBEL + kh * 512 + kq * 8;
    const u16* Bn1 = Bn0 + 16 * NBEL;
#pragma unroll 4
    for (int k = 0; k < 512; k += 32) {
      bf16x8 a0 = ld8bf(A0 + k), a1 = ld8bf(A1 + k);
      bf16x8 b0 = ld8bf(Br0 + k), b1 = ld8bf(Br1 + k);
      Q4(ar, a0, a1, b0, b1);
      bf16x8 c0 = ld8bf(Bz0 + k), c1 = ld8bf(Bz1 + k);
      Q4(az, a0, a1, c0, c1);
      bf16x8 d0 = ld8bf(Bn0 + k), d1 = ld8bf(Bn1 + k);
      Q4(an, a0, a1, d0, d1);
    }
    if (kh == 1) {
      red_write(&lred[wid][0][0], ar, l);
      red_write(&lred[wid][1][0], az, l);
      red_write(&lred[wid][2][0], an, l);
    }
    __syncthreads();
    if (kh == 0) {
      const int base = l * 16;
#pragma unroll
      for (int i = 0; i < 2; ++i)
#pragma unroll
        for (int j = 0; j < 2; ++j)
#pragma unroll
          for (int q = 0; q < 4; ++q) {
            const int row = row0 + i * 16 + kq * 4 + q;
            const int c = col0 + j * 16 + r16;
            const int li = base + (i * 2 + j) * 4 + q;
            const u16* ghrow = ghc + row * 3072;
            const float r = sigm(ar[i][j][q] + lred[wid][0][li] + bih[c] +
                                 bf2f(ghrow[c]));
            const float z = sigm(az[i][j][q] + lred[wid][1][li] + bih[c + 1024] +
                                 bf2f(ghrow[c + 1024]));
            const float n = tanhf(an[i][j][q] + lred[wid][2][li] + bih[c + 2048] +
                                  r * bf2f(ghrow[c + 2048]));
            const float h = hf[row * NBEL + c];
            const float bnew = (1.f - z) * n + z * h;
            hf[row * NBEL + c] = bnew;
            bbf[row * NBEL + c] = f2bf(bnew);
            out[OUT_B + (size_t)t * (NB * NBEL) + row * NBEL + c] = bnew;
          }
    }
    setflag_blk(fG + t);
  } else if (blockIdx.x < 160) {
    if (t >= 1)
      dev_spri(blockIdx.x - 128, wid, kh, r16, kq, l, t - 1,
               hpriPrev, wspri, bspri, npri, out,
               &lred[wid][0][0], &lred[wid][1][0]);
  } else if (blockIdx.x < 288) {
    // ---- hbB: wait GRU ----
    waitflag_blk(fG + t, 128);
    const int g = blockIdx.x - 160, bm = g >> 4, bn = g & 15;
    const int row0 = bm * 64 + (wid >> 1) * 32;
    const int col0 = bn * 64 + (wid & 1) * 32;
    f32x4 acc[2][2]; ZACC(acc);
    const u16* A0 = bbf + (row0 + r16) * NBEL + kh * 512 + kq * 8;
    const u16* A1 = A0 + 16 * NBEL;
    const u16* B0 = wbpos + (size_t)(col0 + r16) * 2048 + kh * 512 + kq * 8;
    const u16* B1 = B0 + 16 * 2048;
#pragma unroll 4
    for (int k = 0; k < 512; k += 32) {
      bf16x8 a0 = ld8bf(A0 + k), a1 = ld8bf(A1 + k);
      bf16x8 b0 = ld8bf(B0 + k), b1 = ld8bf(B1 + k);
      Q4(acc, a0, a1, b0, b1);
    }
    if (kh == 1) red_write(&lred[wid][0][0], acc, l);
    __syncthreads();
    if (kh == 0) {
      red_add(&lred[wid][0][0], acc, l);
#pragma unroll
      for (int i = 0; i < 2; ++i)
#pragma unroll
        for (int j = 0; j < 2; ++j)
#pragma unroll
          for (int q = 0; q < 4; ++q) {
            const int row = row0 + i * 16 + kq * 4 + q;
            const int col = col0 + j * 16 + r16;
            const float v = acc[i][j][q] + hbOc[row * NBEL + col] + bbpos[col];
            hbbf[row * NBEL + col] = f2bf(fmaxf(v, 0.f));
          }
    }
    setflag_blk(fH + t);
  } else if (blockIdx.x < 320) {
    waitflag_blk(fG + t, 128);
    dev_bpri32(blockIdx.x - 288, wid8, r16, kq, bbf, wbpri, bbpri, hpriCur);
    setflag_blk(fB + t);
  } else if (blockIdx.x < 368) {
    if (t + 1 < NT) {
      waitflag_blk(fG + t, 128);
      dev_gh48(blockIdx.x - 320, wid8, r16, kq, bbf, whh, bhh, ghn);
    }
  } else if (blockIdx.x < 400) {
    if (t + 1 < NT)
      dev_hbO32(blockIdx.x - 368, wid8, r16, kq,
                Of + (size_t)(t + 1) * (NB * NBEL), wbpos, hbOn);
  } else if (blockIdx.x < 432) {
    // ---- spos: wait hbB ----
    waitflag_blk(fH + t, 128);
    const int g = blockIdx.x - 400, bm = g >> 2, bn = g & 3;
    const int row0 = bm * 64 + (wid >> 1) * 32;
    const int c0 = bn * 64 + (wid & 1) * 32;
    f32x4 am[2][2], ah[2][2];
    ZACC(am); ZACC(ah);
    const u16* A0 = hbbf + (row0 + r16) * NBEL + kh * 512 + kq * 8;
    const u16* A1 = A0 + 16 * NBEL;
    const u16* Bm0 = wspos + (size_t)(c0 + r16) * NBEL + kh * 512 + kq * 8;
    const u16* Bm1 = Bm0 + 16 * NBEL;
    const u16* Bh0 = wspos + (size_t)(c0 + 256 + r16) * NBEL + kh * 512 + kq * 8;
    const u16* Bh1 = Bh0 + 16 * NBEL;
#pragma unroll 4
    for (int k = 0; k < 512; k += 32) {
      bf16x8 a0 = ld8bf(A0 + k), a1 = ld8bf(A1 + k);
      bf16x8 m0 = ld8bf(Bm0 + k), m1 = ld8bf(Bm1 + k);
      Q4(am, a0, a1, m0, m1);
      bf16x8 h0 = ld8bf(Bh0 + k), h1 = ld8bf(Bh1 + k);
      Q4(ah, a0, a1, h0, h1);
    }
    if (kh == 1) {
      red_write(&lred[wid][0][0], am, l);
      red_write(&lred[wid][1][0], ah, l);
    }
    __syncthreads();
    if (kh == 0) {
      red_add(&lred[wid][0][0], am, l);
      red_add(&lred[wid][1][0], ah, l);
#pragma unroll
      for (int i = 0; i < 2; ++i)
#pragma unroll
        for (int j = 0; j < 2; ++j)
#pragma unroll
          for (int q = 0; q < 4; ++q) {
            const int row = row0 + i * 16 + kq * 4 + q;
            const int c = c0 + j * 16 + r16;
            const float mu = am[i][j][q] + bspos[c];
            const float hq = ah[i][j][q] + bspos[c + 256];
            const float sd = softplus_(hq) + 0.1f;
            const size_t idx = (size_t)t * (NB * NS) + (size_t)row * NS + c;
            const float sq = mu + sd * npos[idx];
            out[OUT_SPOS + idx] = sq;
            out[OUT_MUPOS + idx] = mu;
            out[OUT_STDPOS + idx] = sd;
            const float mn = (t < NT - 1) ? Mptr[(t + 1) * NB + row] : 1.f;
            smask[row * NS + c] = f2bf(sq * mn);
          }
    }
    setflag_blk(fS + t);
  } else {
    if (t + 1 < NT) {
      waitflag_blk(fS + t, 32);
      dev_x64(blockIdx.x - 432, wid8, r16, kq, t + 1, smask, Af, wsa, bsa,
              (u16*)xg);
    } else if (blockIdx.x < 464) {
      // spri(63): wait bpri(63)
      waitflag_blk(fB + t, 32);
      dev_spri(blockIdx.x - 432, wid, kh, r16, kq, l, t,
               hpriCur, wspri, bspri, npri, out,
               &lred[wid][0][0], &lred[wid][1][0]);
    }
  }
}

extern "C" void kernel_launch(void* const* d_in, const int* in_sizes, int n_in,
                              void* d_out, int out_size, void* d_ws, size_t ws_size,
                              hipStream_t stream) {
  const float* s0 = (const float*)d_in[0];
  const float* Af = (const float*)d_in[1];
  const float* b0 = (const float*)d_in[2];
  const float* Of = (const float*)d_in[3];
  const float* Mp = (const float*)d_in[4];
  const float* npri = (const float*)d_in[5];
  const float* npos = (const float*)d_in[6];
  const float* Wsa = (const float*)d_in[7];
  const float* bsa = (const float*)d_in[8];
  const float* Wih = (const float*)d_in[9];
  const float* bih = (const float*)d_in[10];
  const float* Whh = (const float*)d_in[11];
  const float* bhh = (const float*)d_in[12];
  const float* Wbpri = (const float*)d_in[13];
  const float* bbpri = (const float*)d_in[14];
  const float* Wspri = (const float*)d_in[15];
  const float* bspri = (const float*)d_in[16];
  const float* Wbpos = (const float*)d_in[17];
  const float* bbpos = (const float*)d_in[18];
  const float* Wspos = (const float*)d_in[19];
  const float* bspos = (const float*)d_in[20];

  float* out = (float*)d_out;
  char* ws = (char*)d_ws;
  u16* wbase   = (u16*)ws;
  u16* wsa_b   = wbase;
  u16* wih_b   = wbase + 327680;
  u16* whh_b   = wbase + 3473408;
  u16* wbpri_b = wbase + 6619136;
  u16* wspri_b = wbase + 7667712;
  u16* wbpos_b = wbase + 8192000;
  u16* wspos_b = wbase + 10289152;
  // weights end at byte 21,626,880
  u16*   smask = (u16*)  (ws + 21626880);  // [512,256]  bf16
  u16*   bbf   = (u16*)  (ws + 21889024);  // [512,1024] bf16
  float* hf    = (float*)(ws + 22937600);  // [512,1024] f32
  u16*   xg    = (u16*)  (ws + 25034752);  // [512,1024] bf16
  float* hbO0  = (float*)(ws + 26083328);  // [512,1024] f32
  float* hbO1  = (float*)(ws + 28180480);  // [512,1024] f32
  u16*   hbbf  = (u16*)  (ws + 30277632);  // [512,1024] bf16
  u16*   hpri0 = (u16*)  (ws + 31326208);  // [512,1024] bf16
  u16*   hpri1 = (u16*)  (ws + 32374784);  // [512,1024] bf16
  u16*   ghA   = (u16*)  (ws + 33423360);  // [512,3072] bf16 3MB
  u16*   ghB   = (u16*)  (ws + 36569088);  // [512,3072] bf16 3MB
  unsigned* flags = (unsigned*)(ws + 39714816);  // [4*64] u32
  unsigned* fG = flags, *fH = flags + NT, *fS = flags + 2 * NT,
          *fB = flags + 3 * NT;
  // ws end: ~39.7MB

  cvt_weights_k<<<2048, 256, 0, stream>>>(Wsa, Wih, Whh, Wbpri, Wspri, Wbpos,
                                          Wspos, wbase);
  init_carry_k<<<2048, 256, 0, stream>>>(s0, b0, Mp, smask, bbf, hf, flags);
  kX0<<<224, 512, 0, stream>>>(smask, Af, wsa_b, bsa, xg, Of, wbpos_b, hbO0,
                               bbf, whh_b, bhh, ghA);

  for (int t = 0; t < NT; ++t) {
    float* hbOc = (t & 1) ? hbO1 : hbO0;
    float* hbOn = (t & 1) ? hbO0 : hbO1;
    u16* ghc = (t & 1) ? ghB : ghA;
    u16* ghn = (t & 1) ? ghA : ghB;
    u16* hpriCur  = (t & 1) ? hpri1 : hpri0;
    u16* hpriPrev = (t & 1) ? hpri0 : hpri1;
    kS<<<496, 512, 0, stream>>>(xg, wih_b, bih, ghc, hf, bbf, out,
                                hpriPrev, hpriCur, wspri_b, bspri, npri,
                                wbpos_b, bbpos, hbOc, hbbf,
                                wbpri_b, bbpri,
                                whh_b, bhh, ghn,
                                Of, hbOn,
                                wspos_b, bspos, npos, Mp, smask,
                                Af, wsa_b, bsa,
                                fG, fH, fS, fB, t);
  }
}

// Round 13
// 8082.705 us; speedup vs baseline: 1.7547x; 1.7547x over previous
//
#include <hip/hip_runtime.h>
#include <hip/hip_bf16.h>
#include <math.h>

typedef short bf16x8 __attribute__((ext_vector_type(8)));
typedef float f32x4 __attribute__((ext_vector_type(4)));
typedef unsigned short u16;

#define NT 64
#define NB 512
#define NS 256
#define NA 64
#define NBEL 1024

// d_out element offsets (f32 elements)
#define OUT_B      0
#define OUT_SPRI   33554432
#define OUT_MUPRI  41943040
#define OUT_STDPRI 50331648
#define OUT_SPOS   58720256
#define OUT_MUPOS  67108864
#define OUT_STDPOS 75497472

__device__ __forceinline__ f32x4 mfma16(bf16x8 a, bf16x8 b, f32x4 c) {
  return __builtin_amdgcn_mfma_f32_16x16x32_bf16(a, b, c, 0, 0, 0);
}

__device__ __forceinline__ u16 f2bf(float f) {
  union { float f; unsigned u; } v; v.f = f;
  return (u16)((v.u + 0x7FFFu + ((v.u >> 16) & 1u)) >> 16);
}
__device__ __forceinline__ float bf2f(u16 h) {
  union { unsigned u; float f; } v; v.u = ((unsigned)h) << 16; return v.f;
}

__device__ __forceinline__ bf16x8 ld8bf(const u16* p) { return *(const bf16x8*)p; }

__device__ __forceinline__ bf16x8 cvt8(const float* p) {
  const float4 lo = *(const float4*)p;
  const float4 hi = *(const float4*)(p + 4);
  bf16x8 v;
  v[0] = (short)f2bf(lo.x); v[1] = (short)f2bf(lo.y);
  v[2] = (short)f2bf(lo.z); v[3] = (short)f2bf(lo.w);
  v[4] = (short)f2bf(hi.x); v[5] = (short)f2bf(hi.y);
  v[6] = (short)f2bf(hi.z); v[7] = (short)f2bf(hi.w);
  return v;
}

__device__ __forceinline__ float sigm(float x) { return 1.f / (1.f + __expf(-x)); }
__device__ __forceinline__ float softplus_(float x) {
  if (x > 20.f) return x;
  return log1pf(__expf(x));
}

#define ZACC(acc) { acc[0][0] = (f32x4){0.f,0.f,0.f,0.f}; acc[0][1] = (f32x4){0.f,0.f,0.f,0.f}; \
                    acc[1][0] = (f32x4){0.f,0.f,0.f,0.f}; acc[1][1] = (f32x4){0.f,0.f,0.f,0.f}; }

#define Q4(acc, a0v, a1v, b0v, b1v) \
  acc[0][0] = mfma16(a0v, b0v, acc[0][0]); \
  acc[0][1] = mfma16(a0v, b1v, acc[0][1]); \
  acc[1][0] = mfma16(a1v, b0v, acc[1][0]); \
  acc[1][1] = mfma16(a1v, b1v, acc[1][1]);

__device__ __forceinline__ void gtile(f32x4 (&acc)[2][2],
    const u16* __restrict__ A, int lda, const u16* __restrict__ B, int ldb,
    int K, int r16, int kq) {
  const u16* A0 = A + r16 * lda + kq * 8;
  const u16* A1 = A0 + 16 * lda;
  const u16* B0 = B + (size_t)r16 * ldb + kq * 8;
  const u16* B1 = B0 + 16 * ldb;
#pragma unroll 4
  for (int k = 0; k < K; k += 32) {
    bf16x8 a0 = ld8bf(A0 + k), a1 = ld8bf(A1 + k);
    bf16x8 b0 = ld8bf(B0 + k), b1 = ld8bf(B1 + k);
    Q4(acc, a0, a1, b0, b1);
  }
}
__device__ __forceinline__ void gtileF(f32x4 (&acc)[2][2],
    const float* __restrict__ A, int lda, const u16* __restrict__ B, int ldb,
    int K, int r16, int kq) {
  const float* A0 = A + r16 * lda + kq * 8;
  const float* A1 = A0 + 16 * lda;
  const u16* B0 = B + (size_t)r16 * ldb + kq * 8;
  const u16* B1 = B0 + 16 * ldb;
#pragma unroll 2
  for (int k = 0; k < K; k += 32) {
    bf16x8 a0 = cvt8(A0 + k), a1 = cvt8(A1 + k);
    bf16x8 b0 = ld8bf(B0 + k), b1 = ld8bf(B1 + k);
    Q4(acc, a0, a1, b0, b1);
  }
}

__device__ __forceinline__ void red_write(float* L, f32x4 (&acc)[2][2], int l) {
  const int base = l * 16;
#pragma unroll
  for (int i = 0; i < 2; ++i)
#pragma unroll
    for (int j = 0; j < 2; ++j)
#pragma unroll
      for (int q = 0; q < 4; ++q)
        L[base + (i * 2 + j) * 4 + q] = acc[i][j][q];
}
__device__ __forceinline__ void red_add(const float* L, f32x4 (&acc)[2][2], int l) {
  const int base = l * 16;
#pragma unroll
  for (int i = 0; i < 2; ++i)
#pragma unroll
    for (int j = 0; j < 2; ++j)
#pragma unroll
      for (int q = 0; q < 4; ++q)
        acc[i][j][q] += L[base + (i * 2 + j) * 4 + q];
}

// -------- device-scope flag sync (proven R7-R11) --------
__device__ __forceinline__ void setflag_blk(unsigned* f) {
  __syncthreads();
  if (threadIdx.x == 0)
    __hip_atomic_fetch_add(f, 1u, __ATOMIC_RELEASE, __HIP_MEMORY_SCOPE_AGENT);
}
__device__ __forceinline__ void waitflag_blk(unsigned* f, unsigned target) {
  if (threadIdx.x == 0) {
    while (__hip_atomic_load(f, __ATOMIC_RELAXED, __HIP_MEMORY_SCOPE_AGENT) < target)
      __builtin_amdgcn_s_sleep(2);
    (void)__hip_atomic_load(f, __ATOMIC_ACQUIRE, __HIP_MEMORY_SCOPE_AGENT);
  }
  __syncthreads();
}

// -------- P0: weights f32 -> bf16 --------
__global__ __launch_bounds__(256) void cvt_weights_k(
    const float* __restrict__ wsa, const float* __restrict__ wih,
    const float* __restrict__ whh, const float* __restrict__ wbpri,
    const float* __restrict__ wspri, const float* __restrict__ wbpos,
    const float* __restrict__ wspos, u16* __restrict__ dst) {
  const int S0 = 327680;
  const int S1 = S0 + 3145728;
  const int S2 = S1 + 3145728;
  const int S3 = S2 + 1048576;
  const int S4 = S3 + 524288;
  const int S5 = S4 + 2097152;
  const int S6 = S5 + 524288;
  for (int i = blockIdx.x * blockDim.x + threadIdx.x; i < S6;
       i += gridDim.x * blockDim.x) {
    float v;
    if (i < S0) v = wsa[i];
    else if (i < S1) v = wih[i - S0];
    else if (i < S2) v = whh[i - S1];
    else if (i < S3) v = wbpri[i - S2];
    else if (i < S4) v = wspri[i - S3];
    else if (i < S5) v = wbpos[i - S4];
    else v = wspos[i - S5];
    dst[i] = f2bf(v);
  }
}

// -------- P1: init carries + zero flags --------
__global__ __launch_bounds__(256) void init_carry_k(
    const float* __restrict__ s0, const float* __restrict__ b0,
    const float* __restrict__ Mptr, u16* __restrict__ smask,
    u16* __restrict__ bbf, float* __restrict__ hf,
    unsigned* __restrict__ flags) {
  for (int i = blockIdx.x * blockDim.x + threadIdx.x; i < NB * NBEL;
       i += gridDim.x * blockDim.x) {
    float b = b0[i];
    bbf[i] = f2bf(b);
    hf[i] = b;
    if (i < NB * NS) {
      int row = i >> 8;
      smask[i] = f2bf(s0[i] * Mptr[row]);
    }
    if (i < 2048) flags[i] = 0;
  }
}

// -------- device pieces (all byte-identical to R11) --------

// spri: 32 blocks (8 x 4), K-split 8-wave
__device__ __forceinline__ void dev_spri(
    int g, int wid, int kh, int r16, int kq, int l, int tt,
    const u16* __restrict__ hpri, const u16* __restrict__ wspri,
    const float* __restrict__ bspri, const float* __restrict__ npri,
    float* __restrict__ out, float* lred0, float* lred1) {
  const int bm = g >> 2, bn = g & 3;
  const int row0 = bm * 64 + (wid >> 1) * 32;
  const int c0 = bn * 64 + (wid & 1) * 32;
  f32x4 am[2][2], ah[2][2];
  ZACC(am); ZACC(ah);
  const u16* A0 = hpri + (row0 + r16) * NBEL + kh * 512 + kq * 8;
  const u16* A1 = A0 + 16 * NBEL;
  const u16* Bm0 = wspri + (size_t)(c0 + r16) * NBEL + kh * 512 + kq * 8;
  const u16* Bm1 = Bm0 + 16 * NBEL;
  const u16* Bh0 = wspri + (size_t)(c0 + 256 + r16) * NBEL + kh * 512 + kq * 8;
  const u16* Bh1 = Bh0 + 16 * NBEL;
#pragma unroll 4
  for (int k = 0; k < 512; k += 32) {
    bf16x8 a0 = ld8bf(A0 + k), a1 = ld8bf(A1 + k);
    bf16x8 m0 = ld8bf(Bm0 + k), m1 = ld8bf(Bm1 + k);
    Q4(am, a0, a1, m0, m1);
    bf16x8 h0 = ld8bf(Bh0 + k), h1 = ld8bf(Bh1 + k);
    Q4(ah, a0, a1, h0, h1);
  }
  if (kh == 1) {
    red_write(lred0, am, l);
    red_write(lred1, ah, l);
  }
  __syncthreads();
  if (kh == 0) {
    red_add(lred0, am, l);
    red_add(lred1, ah, l);
#pragma unroll
    for (int i = 0; i < 2; ++i)
#pragma unroll
      for (int j = 0; j < 2; ++j)
#pragma unroll
        for (int q = 0; q < 4; ++q) {
          const int row = row0 + i * 16 + kq * 4 + q;
          const int c = c0 + j * 16 + r16;
          const size_t idx = (size_t)tt * (NB * NS) + (size_t)row * NS + c;
          const float mu = am[i][j][q] + bspri[c];
          const float hp = ah[i][j][q] + bspri[c + 256];
          const float sd = softplus_(hp) + 0.1f;
          out[OUT_SPRI + idx] = mu + sd * npri[idx];
          out[OUT_MUPRI + idx] = mu;
          out[OUT_STDPRI + idx] = sd;
        }
  }
}

// x: 64 blocks (8 x 8), 8-wave full-K 64x128 tiles
__device__ __forceinline__ void dev_x64(
    int g, int wid8, int r16, int kq, int t,
    const u16* __restrict__ smask, const float* __restrict__ Af,
    const u16* __restrict__ wsa, const float* __restrict__ bsa,
    u16* __restrict__ xg) {
  const int row0 = (g >> 3) * 64 + (wid8 >> 2) * 32;
  const int col0 = (g & 7) * 128 + (wid8 & 3) * 32;
  f32x4 acc[2][2]; ZACC(acc);
  gtile(acc, smask + row0 * NS, NS, wsa + (size_t)col0 * 320, 320, 256, r16, kq);
  gtileF(acc, Af + (size_t)t * (NB * NA) + (size_t)row0 * NA, NA,
         wsa + (size_t)col0 * 320 + 256, 320, 64, r16, kq);
#pragma unroll
  for (int i = 0; i < 2; ++i)
#pragma unroll
    for (int j = 0; j < 2; ++j)
#pragma unroll
      for (int q = 0; q < 4; ++q) {
        const int row = row0 + i * 16 + kq * 4 + q;
        const int col = col0 + j * 16 + r16;
        xg[row * NBEL + col] = f2bf(fmaxf(acc[i][j][q] + bsa[col], 0.f));
      }
}

// hbO: 64 blocks (8 x 8)
__device__ __forceinline__ void dev_hbO64(
    int g, int wid8, int r16, int kq,
    const float* __restrict__ OfT, const u16* __restrict__ wbpos,
    float* __restrict__ hbOn) {
  const int row0 = (g >> 3) * 64 + (wid8 >> 2) * 32;
  const int col0 = (g & 7) * 128 + (wid8 & 3) * 32;
  f32x4 acc[2][2]; ZACC(acc);
  gtileF(acc, OfT + (size_t)row0 * NBEL, NBEL,
         wbpos + (size_t)col0 * 2048 + 1024, 2048, 1024, r16, kq);
#pragma unroll
  for (int i = 0; i < 2; ++i)
#pragma unroll
    for (int j = 0; j < 2; ++j)
#pragma unroll
      for (int q = 0; q < 4; ++q) {
        const int row = row0 + i * 16 + kq * 4 + q;
        const int col = col0 + j * 16 + r16;
        hbOn[row * NBEL + col] = acc[i][j][q];
      }
}

// gh: 96 blocks (8 x 12), bf16 out
__device__ __forceinline__ void dev_gh96(
    int g, int wid8, int r16, int kq,
    const u16* __restrict__ bsrc, const u16* __restrict__ whh,
    const float* __restrict__ bhh, u16* __restrict__ ghn) {
  const int bm = g / 12, bc = g % 12;
  const int row0 = bm * 64 + (wid8 >> 2) * 32;
#pragma unroll
  for (int jt = 0; jt < 2; ++jt) {
    const int col0 = bc * 256 + (wid8 & 3) * 32 + jt * 128;
    f32x4 acc[2][2]; ZACC(acc);
    gtile(acc, bsrc + row0 * NBEL, NBEL, whh + (size_t)col0 * NBEL, NBEL,
          1024, r16, kq);
#pragma unroll
    for (int i = 0; i < 2; ++i)
#pragma unroll
      for (int j = 0; j < 2; ++j)
#pragma unroll
        for (int q = 0; q < 4; ++q) {
          const int row = row0 + i * 16 + kq * 4 + q;
          const int col = col0 + j * 16 + r16;
          ghn[row * 3072 + col] = f2bf(acc[i][j][q] + bhh[col]);
        }
  }
}

// bpri: 64 blocks (8 x 8), 8-wave full-K
__device__ __forceinline__ void dev_bpri64(
    int g, int wid8, int r16, int kq,
    const u16* __restrict__ bcur, const u16* __restrict__ wbpri,
    const float* __restrict__ bbpri, u16* __restrict__ hpri) {
  const int row0 = (g >> 3) * 64 + (wid8 >> 2) * 32;
  const int col0 = (g & 7) * 128 + (wid8 & 3) * 32;
  f32x4 acc[2][2]; ZACC(acc);
  gtile(acc, bcur + row0 * NBEL, NBEL, wbpri + (size_t)col0 * NBEL, NBEL,
        1024, r16, kq);
#pragma unroll
  for (int i = 0; i < 2; ++i)
#pragma unroll
    for (int j = 0; j < 2; ++j)
#pragma unroll
      for (int q = 0; q < 4; ++q) {
        const int row = row0 + i * 16 + kq * 4 + q;
        const int col = col0 + j * 16 + r16;
        hpri[row * NBEL + col] = f2bf(fmaxf(acc[i][j][q] + bbpri[col], 0.f));
      }
}

// ======================= kX0: x(0) [0..63] | hbO(0) [64..127] | gh(0) [128..223] =======================
__global__ __launch_bounds__(512, 2) void kX0(
    const u16* __restrict__ smask, const float* __restrict__ Af,
    const u16* __restrict__ wsa, const float* __restrict__ bsa,
    u16* __restrict__ xg, const float* __restrict__ Of,
    const u16* __restrict__ wbpos, float* __restrict__ hbO0,
    const u16* __restrict__ bbf, const u16* __restrict__ whh,
    const float* __restrict__ bhh, u16* __restrict__ ghA) {
  const int l = threadIdx.x & 63, r16 = l & 15, kq = l >> 4;
  const int wid8 = threadIdx.x >> 6;
  if (blockIdx.x < 64) {
    dev_x64(blockIdx.x, wid8, r16, kq, 0, smask, Af, wsa, bsa, xg);
  } else if (blockIdx.x < 128) {
    dev_hbO64(blockIdx.x - 64, wid8, r16, kq, Of, wbpos, hbO0);
  } else {
    dev_gh96(blockIdx.x - 128, wid8, r16, kq, bbf, whh, bhh, ghA);
  }
}

// ======================= kG: gi+GRU [0..127] | spri(t-1) [128..159] | hbO(t+1) [160..223] =======================
__global__ __launch_bounds__(512, 2) void kG(
    const u16* __restrict__ xg, const u16* __restrict__ wih,
    const float* __restrict__ bih, const u16* __restrict__ ghc,
    float* __restrict__ hf, u16* __restrict__ bcur, float* __restrict__ out,
    const u16* __restrict__ hpriPrev, const u16* __restrict__ wspri,
    const float* __restrict__ bspri, const float* __restrict__ npri,
    const float* __restrict__ Of, const u16* __restrict__ wbpos,
    float* __restrict__ hbOn, int t) {
  __shared__ float lred[4][3][1024];  // 48KB
  const int l = threadIdx.x & 63, r16 = l & 15, kq = l >> 4;
  const int wid8 = threadIdx.x >> 6;
  const int wid = wid8 & 3, kh = wid8 >> 2;
  if (blockIdx.x < 128) {
    const int g = blockIdx.x, bm = g >> 4, bn = g & 15;
    const int row0 = bm * 64 + (wid >> 1) * 32;
    const int col0 = bn * 64 + (wid & 1) * 32;
    f32x4 ar[2][2], az[2][2], an[2][2];
    ZACC(ar); ZACC(az); ZACC(an);
    const u16* A0 = xg + (row0 + r16) * NBEL + kh * 512 + kq * 8;
    const u16* A1 = A0 + 16 * NBEL;
    const u16* Br0 = wih + (size_t)(col0 + r16) * NBEL + kh * 512 + kq * 8;
    const u16* Br1 = Br0 + 16 * NBEL;
    const u16* Bz0 = wih + (size_t)(col0 + 1024 + r16) * NBEL + kh * 512 + kq * 8;
    const u16* Bz1 = Bz0 + 16 * NBEL;
    const u16* Bn0 = wih + (size_t)(col0 + 2048 + r16) * NBEL + kh * 512 + kq * 8;
    const u16* Bn1 = Bn0 + 16 * NBEL;
#pragma unroll 4
    for (int k = 0; k < 512; k += 32) {
      bf16x8 a0 = ld8bf(A0 + k), a1 = ld8bf(A1 + k);
      bf16x8 b0 = ld8bf(Br0 + k), b1 = ld8bf(Br1 + k);
      Q4(ar, a0, a1, b0, b1);
      bf16x8 c0 = ld8bf(Bz0 + k), c1 = ld8bf(Bz1 + k);
      Q4(az, a0, a1, c0, c1);
      bf16x8 d0 = ld8bf(Bn0 + k), d1 = ld8bf(Bn1 + k);
      Q4(an, a0, a1, d0, d1);
    }
    if (kh == 1) {
      red_write(&lred[wid][0][0], ar, l);
      red_write(&lred[wid][1][0], az, l);
      red_write(&lred[wid][2][0], an, l);
    }
    __syncthreads();
    if (kh == 0) {
      const int base = l * 16;
#pragma unroll
      for (int i = 0; i < 2; ++i)
#pragma unroll
        for (int j = 0; j < 2; ++j)
#pragma unroll
          for (int q = 0; q < 4; ++q) {
            const int row = row0 + i * 16 + kq * 4 + q;
            const int c = col0 + j * 16 + r16;
            const int li = base + (i * 2 + j) * 4 + q;
            const u16* ghrow = ghc + row * 3072;
            const float r = sigm(ar[i][j][q] + lred[wid][0][li] + bih[c] +
                                 bf2f(ghrow[c]));
            const float z = sigm(az[i][j][q] + lred[wid][1][li] + bih[c + 1024] +
                                 bf2f(ghrow[c + 1024]));
            const float n = tanhf(an[i][j][q] + lred[wid][2][li] + bih[c + 2048] +
                                  r * bf2f(ghrow[c + 2048]));
            const float h = hf[row * NBEL + c];
            const float bnew = (1.f - z) * n + z * h;
            hf[row * NBEL + c] = bnew;
            bcur[row * NBEL + c] = f2bf(bnew);
            out[OUT_B + (size_t)t * (NB * NBEL) + row * NBEL + c] = bnew;
          }
    }
  } else if (blockIdx.x < 160) {
    if (t >= 1)
      dev_spri(blockIdx.x - 128, wid, kh, r16, kq, l, t - 1,
               hpriPrev, wspri, bspri, npri, out,
               &lred[wid][0][0], &lred[wid][1][0]);
  } else {
    if (t + 1 < NT)
      dev_hbO64(blockIdx.x - 160, wid8, r16, kq,
                Of + (size_t)(t + 1) * (NB * NBEL), wbpos, hbOn);
  }
}

// ======================= kM: hbB [0..127] | bpri [128..191] | gh(t+1) [192..287]
//                         | spos [288..319] | x(t+1) [320..383] | spri(63) [384..415] =======================
__global__ __launch_bounds__(512, 2) void kM(
    const u16* __restrict__ bcur, const u16* __restrict__ wbpos,
    const float* __restrict__ bbpos, const float* __restrict__ hbOc,
    u16* __restrict__ hbbf,
    const u16* __restrict__ wbpri, const float* __restrict__ bbpri,
    u16* __restrict__ hpriCur,
    const u16* __restrict__ whh, const float* __restrict__ bhh,
    u16* __restrict__ ghn,
    const u16* __restrict__ wspos, const float* __restrict__ bspos,
    const float* __restrict__ npos, const float* __restrict__ Mptr,
    u16* __restrict__ smask,
    const float* __restrict__ Af, const u16* __restrict__ wsa,
    const float* __restrict__ bsa, u16* __restrict__ xg,
    const u16* __restrict__ wspri, const float* __restrict__ bspri,
    const float* __restrict__ npri,
    float* __restrict__ out,
    unsigned* __restrict__ fH8, unsigned* __restrict__ fS8,
    unsigned* __restrict__ fB, int t) {
  __shared__ float lred[4][2][1024];  // 32KB
  const int l = threadIdx.x & 63, r16 = l & 15, kq = l >> 4;
  const int wid8 = threadIdx.x >> 6;
  const int wid = wid8 & 3, kh = wid8 >> 2;
  if (blockIdx.x < 128) {
    // ---- hbB: K-split 8-wave; per-row-group flag ----
    const int g = blockIdx.x, bm = g >> 4, bn = g & 15;
    const int row0 = bm * 64 + (wid >> 1) * 32;
    const int col0 = bn * 64 + (wid & 1) * 32;
    f32x4 acc[2][2]; ZACC(acc);
    const u16* A0 = bcur + (row0 + r16) * NBEL + kh * 512 + kq * 8;
    const u16* A1 = A0 + 16 * NBEL;
    const u16* B0 = wbpos + (size_t)(col0 + r16) * 2048 + kh * 512 + kq * 8;
    const u16* B1 = B0 + 16 * 2048;
#pragma unroll 4
    for (int k = 0; k < 512; k += 32) {
      bf16x8 a0 = ld8bf(A0 + k), a1 = ld8bf(A1 + k);
      bf16x8 b0 = ld8bf(B0 + k), b1 = ld8bf(B1 + k);
      Q4(acc, a0, a1, b0, b1);
    }
    if (kh == 1) red_write(&lred[wid][0][0], acc, l);
    __syncthreads();
    if (kh == 0) {
      red_add(&lred[wid][0][0], acc, l);
#pragma unroll
      for (int i = 0; i < 2; ++i)
#pragma unroll
        for (int j = 0; j < 2; ++j)
#pragma unroll
          for (int q = 0; q < 4; ++q) {
            const int row = row0 + i * 16 + kq * 4 + q;
            const int col = col0 + j * 16 + r16;
            const float v = acc[i][j][q] + hbOc[row * NBEL + col] + bbpos[col];
            hbbf[row * NBEL + col] = f2bf(fmaxf(v, 0.f));
          }
    }
    setflag_blk(fH8 + t * 8 + bm);
  } else if (blockIdx.x < 192) {
    dev_bpri64(blockIdx.x - 128, wid8, r16, kq, bcur, wbpri, bbpri, hpriCur);
    setflag_blk(fB + t);
  } else if (blockIdx.x < 288) {
    if (t + 1 < NT)
      dev_gh96(blockIdx.x - 192, wid8, r16, kq, bcur, whh, bhh, ghn);
  } else if (blockIdx.x < 320) {
    // ---- spos: wait own row group of hbB (16 blocks) ----
    const int g = blockIdx.x - 288, bm = g >> 2, bn = g & 3;
    waitflag_blk(fH8 + t * 8 + bm, 16);
    const int row0 = bm * 64 + (wid >> 1) * 32;
    const int c0 = bn * 64 + (wid & 1) * 32;
    f32x4 am[2][2], ah[2][2];
    ZACC(am); ZACC(ah);
    const u16* A0 = hbbf + (row0 + r16) * NBEL + kh * 512 + kq * 8;
    const u16* A1 = A0 + 16 * NBEL;
    const u16* Bm0 = wspos + (size_t)(c0 + r16) * NBEL + kh * 512 + kq * 8;
    const u16* Bm1 = Bm0 + 16 * NBEL;
    const u16* Bh0 = wspos + (size_t)(c0 + 256 + r16) * NBEL + kh * 512 + kq * 8;
    const u16* Bh1 = Bh0 + 16 * NBEL;
#pragma unroll 4
    for (int k = 0; k < 512; k += 32) {
      bf16x8 a0 = ld8bf(A0 + k), a1 = ld8bf(A1 + k);
      bf16x8 m0 = ld8bf(Bm0 + k), m1 = ld8bf(Bm1 + k);
      Q4(am, a0, a1, m0, m1);
      bf16x8 h0 = ld8bf(Bh0 + k), h1 = ld8bf(Bh1 + k);
      Q4(ah, a0, a1, h0, h1);
    }
    if (kh == 1) {
      red_write(&lred[wid][0][0], am, l);
      red_write(&lred[wid][1][0], ah, l);
    }
    __syncthreads();
    if (kh == 0) {
      red_add(&lred[wid][0][0], am, l);
      red_add(&lred[wid][1][0], ah, l);
#pragma unroll
      for (int i = 0; i < 2; ++i)
#pragma unroll
        for (int j = 0; j < 2; ++j)
#pragma unroll
          for (int q = 0; q < 4; ++q) {
            const int row = row0 + i * 16 + kq * 4 + q;
            const int c = c0 + j * 16 + r16;
            const float mu = am[i][j][q] + bspos[c];
            const float hq = ah[i][j][q] + bspos[c + 256];
            const float sd = softplus_(hq) + 0.1f;
            const size_t idx = (size_t)t * (NB * NS) + (size_t)row * NS + c;
            const float sq = mu + sd * npos[idx];
            out[OUT_SPOS + idx] = sq;
            out[OUT_MUPOS + idx] = mu;
            out[OUT_STDPOS + idx] = sd;
            const float mn = (t < NT - 1) ? Mptr[(t + 1) * NB + row] : 1.f;
            smask[row * NS + c] = f2bf(sq * mn);
          }
    }
    setflag_blk(fS8 + t * 8 + bm);
  } else if (blockIdx.x < 384) {
    // ---- x(t+1): wait own row group of spos (4 blocks) ----
    if (t + 1 >= NT) return;
    const int g = blockIdx.x - 320;
    waitflag_blk(fS8 + t * 8 + (g >> 3), 4);
    dev_x64(g, wid8, r16, kq, t + 1, smask, Af, wsa, bsa, xg);
  } else {
    // ---- spri(63): wait bpri(63) ----
    if (t != NT - 1) return;
    waitflag_blk(fB + t, 64);
    dev_spri(blockIdx.x - 384, wid, kh, r16, kq, l, t,
             hpriCur, wspri, bspri, npri, out,
             &lred[wid][0][0], &lred[wid][1][0]);
  }
}

extern "C" void kernel_launch(void* const* d_in, const int* in_sizes, int n_in,
                              void* d_out, int out_size, void* d_ws, size_t ws_size,
                              hipStream_t stream) {
  const float* s0 = (const float*)d_in[0];
  const float* Af = (const float*)d_in[1];
  const float* b0 = (const float*)d_in[2];
  const float* Of = (const float*)d_in[3];
  const float* Mp = (const float*)d_in[4];
  const float* npri = (const float*)d_in[5];
  const float* npos = (const float*)d_in[6];
  const float* Wsa = (const float*)d_in[7];
  const float* bsa = (const float*)d_in[8];
  const float* Wih = (const float*)d_in[9];
  const float* bih = (const float*)d_in[10];
  const float* Whh = (const float*)d_in[11];
  const float* bhh = (const float*)d_in[12];
  const float* Wbpri = (const float*)d_in[13];
  const float* bbpri = (const float*)d_in[14];
  const float* Wspri = (const float*)d_in[15];
  const float* bspri = (const float*)d_in[16];
  const float* Wbpos = (const float*)d_in[17];
  const float* bbpos = (const float*)d_in[18];
  const float* Wspos = (const float*)d_in[19];
  const float* bspos = (const float*)d_in[20];

  float* out = (float*)d_out;
  char* ws = (char*)d_ws;
  u16* wbase   = (u16*)ws;
  u16* wsa_b   = wbase;
  u16* wih_b   = wbase + 327680;
  u16* whh_b   = wbase + 3473408;
  u16* wbpri_b = wbase + 6619136;
  u16* wspri_b = wbase + 7667712;
  u16* wbpos_b = wbase + 8192000;
  u16* wspos_b = wbase + 10289152;
  // weights end at byte 21,626,880
  u16*   smask = (u16*)  (ws + 21626880);  // [512,256]  bf16
  u16*   bbf   = (u16*)  (ws + 21889024);  // [512,1024] bf16
  float* hf    = (float*)(ws + 22937600);  // [512,1024] f32
  u16*   xg    = (u16*)  (ws + 25034752);  // [512,1024] bf16
  float* hbO0  = (float*)(ws + 26083328);  // [512,1024] f32
  float* hbO1  = (float*)(ws + 28180480);  // [512,1024] f32
  u16*   hbbf  = (u16*)  (ws + 30277632);  // [512,1024] bf16
  u16*   hpri0 = (u16*)  (ws + 31326208);  // [512,1024] bf16
  u16*   hpri1 = (u16*)  (ws + 32374784);  // [512,1024] bf16
  u16*   ghA   = (u16*)  (ws + 33423360);  // [512,3072] bf16 3MB
  u16*   ghB   = (u16*)  (ws + 36569088);  // [512,3072] bf16 3MB
  unsigned* flags = (unsigned*)(ws + 39714816);  // 2048 u32
  unsigned* fH8 = flags;            // [64*8]
  unsigned* fS8 = flags + 512;      // [64*8]
  unsigned* fB  = flags + 1024;     // [64]
  // ws end: ~39.7MB

  cvt_weights_k<<<2048, 256, 0, stream>>>(Wsa, Wih, Whh, Wbpri, Wspri, Wbpos,
                                          Wspos, wbase);
  init_carry_k<<<2048, 256, 0, stream>>>(s0, b0, Mp, smask, bbf, hf, flags);
  kX0<<<224, 512, 0, stream>>>(smask, Af, wsa_b, bsa, xg, Of, wbpos_b, hbO0,
                               bbf, whh_b, bhh, ghA);

  for (int t = 0; t < NT; ++t) {
    float* hbOc = (t & 1) ? hbO1 : hbO0;
    float* hbOn = (t & 1) ? hbO0 : hbO1;
    u16* ghc = (t & 1) ? ghB : ghA;
    u16* ghn = (t & 1) ? ghA : ghB;
    u16* hpriCur  = (t & 1) ? hpri1 : hpri0;
    u16* hpriPrev = (t & 1) ? hpri0 : hpri1;
    kG<<<224, 512, 0, stream>>>(xg, wih_b, bih, ghc, hf, bbf, out,
                                hpriPrev, wspri_b, bspri, npri,
                                Of, wbpos_b, hbOn, t);
    kM<<<416, 512, 0, stream>>>(bbf, wbpos_b, bbpos, hbOc, hbbf,
                                wbpri_b, bbpri, hpriCur,
                                whh_b, bhh, ghn,
                                wspos_b, bspos, npos, Mp, smask,
                                Af, wsa_b, bsa, xg,
                                wspri_b, bspri, npri,
                                out, fH8, fS8, fB, t);
  }
}